// Round 12
// baseline (437.790 us; speedup 1.0000x reference)
//
#include <hip/hip_runtime.h>

#define NEG_SLOPE 0.2f

typedef __attribute__((ext_vector_type(8))) short bf16x8;
typedef __attribute__((ext_vector_type(8))) unsigned short u16x8;
typedef __attribute__((ext_vector_type(4))) float f32x4;

__device__ __forceinline__ float lrelu(float x) { return fmaxf(x, NEG_SLOPE * x); }

__device__ __forceinline__ float bf2f(unsigned short u) {
  return __uint_as_float(((unsigned int)u) << 16);
}
__device__ __forceinline__ unsigned short f2bf(float f) {
  unsigned int u = __float_as_uint(f);
  u += 0x7fffu + ((u >> 16) & 1u);   // round-to-nearest-even
  return (unsigned short)(u >> 16);
}

// ---------------- CSR build (by destination), self-loop first ----------------
// scalar 1-edge/thread: max TLP for L2 atomics (int4 chain variant regressed +26us, R11)
__global__ void hist_kernel(const int* __restrict__ dst, int* __restrict__ deg, int e) {
  int i = blockIdx.x * blockDim.x + threadIdx.x;
  if (i < e) atomicAdd(&deg[dst[i]], 1);
}

// phase A: per-block (1024 elems) local exclusive scan of (deg[i]+1); block sums out.
__global__ __launch_bounds__(256) void scan_a(const int* __restrict__ deg, int* __restrict__ rowp,
                                              int* __restrict__ bsum, int n) {
  __shared__ int s[256];
  int t = threadIdx.x;
  int base = blockIdx.x * 1024 + t * 4;
  int d0 = (base + 0 < n) ? deg[base + 0] + 1 : 0;
  int d1 = (base + 1 < n) ? deg[base + 1] + 1 : 0;
  int d2 = (base + 2 < n) ? deg[base + 2] + 1 : 0;
  int d3 = (base + 3 < n) ? deg[base + 3] + 1 : 0;
  s[t] = d0 + d1 + d2 + d3;
  __syncthreads();
  for (int off = 1; off < 256; off <<= 1) {
    int v = 0;
    if (t >= off) v = s[t - off];
    __syncthreads();
    if (t >= off) s[t] += v;
    __syncthreads();
  }
  int p = (t == 0) ? 0 : s[t - 1];
  if (base + 0 < n) rowp[base + 0] = p;
  p += d0;
  if (base + 1 < n) rowp[base + 1] = p;
  p += d1;
  if (base + 2 < n) rowp[base + 2] = p;
  p += d2;
  if (base + 3 < n) rowp[base + 3] = p;
  if (t == 255) bsum[blockIdx.x] = s[255];
}

// phase B: single wave exclusive-scans <=64 block sums; bpre[64] = grand total.
__global__ void scan_b(const int* __restrict__ bsum, int* __restrict__ bpre, int nb) {
  int t = threadIdx.x;  // 64 threads = 1 wave
  int v = (t < nb) ? bsum[t] : 0;
  int orig = v;
#pragma unroll
  for (int off = 1; off < 64; off <<= 1) {
    int u = __shfl_up(v, off);
    if (t >= off) v += u;
  }
  bpre[t] = v - orig;
  if (t == 63) bpre[64] = v;
}

// phase C: add block prefixes; fused init_csr (self-loop slot 0).
__global__ void scan_c(int* __restrict__ rowp, const int* __restrict__ bpre,
                       int* __restrict__ cnt, int* __restrict__ col, int n) {
  int i = blockIdx.x * blockDim.x + threadIdx.x;
  if (i < n) {
    int r = rowp[i] + bpre[i >> 10];
    rowp[i] = r;
    cnt[i] = 1;       // slot 0 = self loop
    col[r] = i;
  }
  if (i == 0) rowp[n] = bpre[64];
}

__global__ void scatter_kernel(const int* __restrict__ src, const int* __restrict__ dst,
                               const int* __restrict__ rowp, int* __restrict__ cnt,
                               int* __restrict__ col, int e) {
  int i = blockIdx.x * blockDim.x + threadIdx.x;
  if (i < e) {
    int d = dst[i];
    int pos = rowp[d] + atomicAdd(&cnt[d], 1);
    col[pos] = src[i];
  }
}

// ---------------- prep: fold a_src/a_dst into W + swizzle to MFMA B-frag; blocks>=3 zero deg ----
__global__ __launch_bounds__(256) void prep_kernel(
    const float* __restrict__ W0, const float* __restrict__ as0, const float* __restrict__ ad0,
    const float* __restrict__ W1, const float* __restrict__ as1, const float* __restrict__ ad1,
    const float* __restrict__ W2, const float* __restrict__ as2, const float* __restrict__ ad2,
    unsigned short* __restrict__ Wsw, unsigned short* __restrict__ Wasw,
    int* __restrict__ deg, int n_nodes) {
  if (blockIdx.x >= 3) {    // deg zero-fill
    int i = ((blockIdx.x - 3) * 256 + threadIdx.x) * 4;
    if (i + 4 <= n_nodes) *(int4*)(deg + i) = make_int4(0, 0, 0, 0);
    else for (int j = i; j < n_nodes; ++j) deg[j] = 0;
    return;
  }
  __shared__ float wa[512];
  int l = blockIdx.x;
  const float* W  = l == 0 ? W0  : l == 1 ? W1  : W2;
  const float* as = l == 0 ? as0 : l == 1 ? as1 : as2;
  const float* ad = l == 0 ? ad0 : l == 1 ? ad1 : ad2;
  int t = threadIdx.x;          // 256 threads
  {
    int k = t >> 2, h = t & 3;
    float ss = 0.f, sd = 0.f;
    for (int c = 0; c < 64; ++c) {
      float w = W[k * 256 + h * 64 + c];
      ss += w * as[h * 64 + c];
      sd += w * ad[h * 64 + c];
    }
    wa[k * 8 + h] = ss;
    wa[k * 8 + 4 + h] = sd;
  }
  __syncthreads();
  for (int s = t; s < 2048; s += 256) {
    int nt = s >> 7, kk = (s >> 6) & 1, lane = s & 63;
    int kq = lane >> 4, r = lane & 15;
#pragma unroll
    for (int j = 0; j < 8; ++j) {
      int k = kk * 32 + kq * 8 + j;
      Wsw[(size_t)l * 16384 + (size_t)s * 8 + j] = f2bf(W[k * 256 + nt * 16 + r]);
    }
  }
  if (t < 128) {
    int lane = t & 63, kq = lane >> 4, r = lane & 15;
    int kk = t >> 6;
#pragma unroll
    for (int j = 0; j < 8; ++j) {
      int k = kk * 32 + kq * 8 + j;
      float v = (r < 8) ? wa[k * 8 + r] : 0.f;
      Wasw[l * 1024 + t * 8 + j] = f2bf(v);
    }
  }
}

// ---------------- hw(bf16) = h @ W via MFMA + attention logits ----------------
// FIRST: h rows computed in-block from x (fused input projection, no global h0 buffer).
template <bool FIRST>
__global__ __launch_bounds__(256) void hw_kernel(const unsigned short* __restrict__ hb,
                                                 const float* __restrict__ x,
                                                 const float* __restrict__ Wp,
                                                 const float* __restrict__ bp,
                                                 const unsigned short* __restrict__ Wsw,
                                                 const unsigned short* __restrict__ Wasw,
                                                 unsigned short* __restrict__ hwb,
                                                 float* __restrict__ al_s, float* __restrict__ al_d,
                                                 int n_nodes) {
  __shared__ unsigned short st[64][264];   // epilogue staging; head aliased as h-tile for FIRST
  unsigned short (*hs)[72] = reinterpret_cast<unsigned short(*)[72]>(&st[0][0]);
  int t = threadIdx.x;
  int w = t >> 6, lane = t & 63;
  int kq = lane >> 4, r16 = lane & 15;
  int n0 = blockIdx.x << 6;

  if constexpr (FIRST) {
    __shared__ float wp_s[1024];
    __shared__ float bp_s[64];
    for (int i = t; i < 1024; i += 256) wp_s[i] = Wp[i];
    if (t < 64) bp_s[t] = bp[t];
    __syncthreads();
#pragma unroll
    for (int i = 0; i < 16; ++i) {
      int r = i * 4 + w;
      int row = n0 + r;
      float acc = 0.f;
      if (row < n_nodes) {
        acc = bp_s[lane];
        const float* xr = x + (size_t)row * 16;
#pragma unroll
        for (int k = 0; k < 16; ++k) acc += xr[k] * wp_s[k * 64 + lane];
        acc = fmaxf(acc, 0.f);
      }
      hs[r][lane] = f2bf(acc);
    }
    __syncthreads();
  }

  // A fragments: 4 m-tiles x 2 k-steps
  bf16x8 a[4][2];
#pragma unroll
  for (int m = 0; m < 4; ++m) {
    if constexpr (FIRST) {
      a[m][0] = *(const bf16x8*)&hs[m * 16 + r16][kq * 8];
      a[m][1] = *(const bf16x8*)&hs[m * 16 + r16][kq * 8 + 32];
    } else {
      int row = min(n0 + m * 16 + r16, n_nodes - 1);
      const unsigned short* p = hb + (size_t)row * 64 + kq * 8;
      a[m][0] = *(const bf16x8*)(p);
      a[m][1] = *(const bf16x8*)(p + 32);
    }
  }
  // B fragments: 4 local n-tiles x 2 k-steps
  bf16x8 b[4][2];
#pragma unroll
  for (int nt = 0; nt < 4; ++nt) {
    int ntg = w * 4 + nt;
    const unsigned short* p = Wsw + ((size_t)ntg * 128 + lane) * 8;
    b[nt][0] = *(const bf16x8*)(p);
    b[nt][1] = *(const bf16x8*)(p + 512);
  }

  f32x4 acc[4][4];
#pragma unroll
  for (int m = 0; m < 4; ++m)
#pragma unroll
    for (int nt = 0; nt < 4; ++nt) acc[m][nt] = (f32x4){0.f, 0.f, 0.f, 0.f};

#pragma unroll
  for (int m = 0; m < 4; ++m)
#pragma unroll
    for (int nt = 0; nt < 4; ++nt) {
      acc[m][nt] = __builtin_amdgcn_mfma_f32_16x16x32_bf16(a[m][0], b[nt][0], acc[m][nt], 0, 0, 0);
      acc[m][nt] = __builtin_amdgcn_mfma_f32_16x16x32_bf16(a[m][1], b[nt][1], acc[m][nt], 0, 0, 0);
    }

  __syncthreads();   // all waves done reading hs (aliases st) before staging
  // stage C into LDS (C/D mapping: col=lane&15, row=(lane>>4)*4+reg)
#pragma unroll
  for (int m = 0; m < 4; ++m)
#pragma unroll
    for (int j = 0; j < 4; ++j) {
      int row = m * 16 + kq * 4 + j;
#pragma unroll
      for (int nt = 0; nt < 4; ++nt)
        st[row][(w * 4 + nt) * 16 + r16] = f2bf(acc[m][nt][j]);
    }
  __syncthreads();

  // coalesced stores: each instr = 32 lanes x 16B = one full 512B row
  int rmax = min(64, n_nodes - n0);
  for (int i = t; i < (rmax << 5); i += 256) {
    int row = i >> 5, ch = i & 31;
    *(u16x8*)(hwb + (size_t)(n0 + row) * 256 + ch * 8) = *(const u16x8*)(&st[row][ch * 8]);
  }

  // attention logits: wave w handles m-tile w; B = folded Wa (8 valid cols)
  bf16x8 ba0 = *(const bf16x8*)(Wasw + lane * 8);
  bf16x8 ba1 = *(const bf16x8*)(Wasw + (64 + lane) * 8);
  f32x4 accl = (f32x4){0.f, 0.f, 0.f, 0.f};
  accl = __builtin_amdgcn_mfma_f32_16x16x32_bf16(a[w][0], ba0, accl, 0, 0, 0);
  accl = __builtin_amdgcn_mfma_f32_16x16x32_bf16(a[w][1], ba1, accl, 0, 0, 0);
  if (r16 < 8) {
#pragma unroll
    for (int j = 0; j < 4; ++j) {
      int row = n0 + w * 16 + kq * 4 + j;
      if (row < n_nodes) {
        if (r16 < 4) al_s[row * 4 + r16] = accl[j];
        else         al_d[row * 4 + (r16 - 4)] = accl[j];
      }
    }
  }
}

// ---------------- aggregate: wave per node, two edges per iteration ----------------
__global__ __launch_bounds__(256) void gat_agg(const int* __restrict__ rowp, const int* __restrict__ col,
                                               const float* __restrict__ alS, const float* __restrict__ alD,
                                               const unsigned short* __restrict__ hwb,
                                               const float* __restrict__ bias,
                                               unsigned short* __restrict__ hout,
                                               int n_nodes) {
  __shared__ uint2 pw[4][64 * 4];   // [wave][edge*4 + head] = (byte addr, w)
  int t = threadIdx.x;
  int wslot = t >> 6, lane = t & 63;
  int node = blockIdx.x * 4 + wslot;
  if (node >= n_nodes) return;      // whole wave exits together
  int base = rowp[node];
  int degv = rowp[node + 1] - base;
  int l31 = lane & 31;
  int half = lane >> 5;                               // which edge of the pair
  int headw = l31 >> 3;                               // head owning this lane's 8 channels
  unsigned int laneoff = (unsigned int)l31 << 4;      // 16B per lane within 512B row
  float4 ald4 = *(const float4*)(alD + (size_t)node * 4);

  float a0 = 0.f, a1 = 0.f, a2 = 0.f, a3 = 0.f;
  float a4 = 0.f, a5 = 0.f, a6 = 0.f, a7 = 0.f, denom = 0.f;

  for (int c0 = 0; c0 < degv; c0 += 64) {
    int cnt = min(64, degv - c0);
    {
      unsigned int ab = 0u;
      float w0 = 0.f, w1 = 0.f, w2 = 0.f, w3 = 0.f;
      if (lane < cnt) {
        int s = col[base + c0 + lane];                // coalesced
        float4 as4 = *(const float4*)(alS + (size_t)s * 4);
        ab = (unsigned int)s << 9;                    // byte addr of hwb row
        w0 = __expf(lrelu(as4.x + ald4.x));
        w1 = __expf(lrelu(as4.y + ald4.y));
        w2 = __expf(lrelu(as4.z + ald4.z));
        w3 = __expf(lrelu(as4.w + ald4.w));
      }
      uint4* pd = (uint4*)&pw[wslot][lane * 4];
      pd[0] = make_uint4(ab, __float_as_uint(w0), ab, __float_as_uint(w1));
      pd[1] = make_uint4(ab, __float_as_uint(w2), ab, __float_as_uint(w3));
    }
    // wave-synchronous: same wave wrote, same wave reads (lgkmcnt auto-inserted)
    int iters = (cnt + 1) >> 1;
#pragma unroll 4
    for (int i = 0; i < iters; ++i) {
      int e = i * 2 + half;
      uint2 p = pw[wslot][e * 4 + headw];             // one ds_read_b64
      float w = __uint_as_float(p.y);
      uint4 v = *(const uint4*)((const char*)hwb + (p.x + laneoff));  // independent gather
      denom += w;
      a0 += w * __uint_as_float(v.x << 16);
      a1 += w * __uint_as_float(v.x & 0xffff0000u);
      a2 += w * __uint_as_float(v.y << 16);
      a3 += w * __uint_as_float(v.y & 0xffff0000u);
      a4 += w * __uint_as_float(v.z << 16);
      a5 += w * __uint_as_float(v.z & 0xffff0000u);
      a6 += w * __uint_as_float(v.w << 16);
      a7 += w * __uint_as_float(v.w & 0xffff0000u);
    }
  }

  // fold the two halves (edge-interleave), then per-head normalize
  denom += __shfl_xor(denom, 32);
  a0 += __shfl_xor(a0, 32); a1 += __shfl_xor(a1, 32);
  a2 += __shfl_xor(a2, 32); a3 += __shfl_xor(a3, 32);
  a4 += __shfl_xor(a4, 32); a5 += __shfl_xor(a5, 32);
  a6 += __shfl_xor(a6, 32); a7 += __shfl_xor(a7, 32);
  float inv = 1.f / denom;
  a0 *= inv; a1 *= inv; a2 *= inv; a3 *= inv;
  a4 *= inv; a5 *= inv; a6 *= inv; a7 *= inv;

  // head mean: channel (l31&7)*8+j lives at lanes {l31&7, +8, +16, +24}
  a0 += __shfl_xor(a0, 8); a0 += __shfl_xor(a0, 16);
  a1 += __shfl_xor(a1, 8); a1 += __shfl_xor(a1, 16);
  a2 += __shfl_xor(a2, 8); a2 += __shfl_xor(a2, 16);
  a3 += __shfl_xor(a3, 8); a3 += __shfl_xor(a3, 16);
  a4 += __shfl_xor(a4, 8); a4 += __shfl_xor(a4, 16);
  a5 += __shfl_xor(a5, 8); a5 += __shfl_xor(a5, 16);
  a6 += __shfl_xor(a6, 8); a6 += __shfl_xor(a6, 16);
  a7 += __shfl_xor(a7, 8); a7 += __shfl_xor(a7, 16);

  if (lane < 8) {
    const float* bp = bias + lane * 8;
    float4 b0 = *(const float4*)(bp);
    float4 b1 = *(const float4*)(bp + 4);
    ushort4 o0, o1;
    o0.x = f2bf(fmaxf(0.25f * a0 + b0.x, 0.f));
    o0.y = f2bf(fmaxf(0.25f * a1 + b0.y, 0.f));
    o0.z = f2bf(fmaxf(0.25f * a2 + b0.z, 0.f));
    o0.w = f2bf(fmaxf(0.25f * a3 + b0.w, 0.f));
    o1.x = f2bf(fmaxf(0.25f * a4 + b1.x, 0.f));
    o1.y = f2bf(fmaxf(0.25f * a5 + b1.y, 0.f));
    o1.z = f2bf(fmaxf(0.25f * a6 + b1.z, 0.f));
    o1.w = f2bf(fmaxf(0.25f * a7 + b1.w, 0.f));
    unsigned short* op = hout + (size_t)node * 64 + lane * 8;
    *(ushort4*)(op) = o0;
    *(ushort4*)(op + 4) = o1;
  }
}

// ---------------- fused global mean pool + output projection ----------------
__global__ __launch_bounds__(256) void poolout_kernel(const unsigned short* __restrict__ h,
                                                      const int* __restrict__ batch,
                                                      const float* __restrict__ Wo,
                                                      const float* __restrict__ bo,
                                                      float* __restrict__ out, int n_nodes) {
  int g = blockIdx.x;
  int lo = 0, hi = n_nodes;
  while (lo < hi) { int mid = (lo + hi) >> 1; if (batch[mid] < g) lo = mid + 1; else hi = mid; }
  int s = lo;
  hi = n_nodes;
  while (lo < hi) { int mid = (lo + hi) >> 1; if (batch[mid] < g + 1) lo = mid + 1; else hi = mid; }
  int e = lo;

  int t = threadIdx.x, c = t & 63, wv = t >> 6;
  float acc = 0.f;
  for (int r = s + wv; r < e; r += 4) acc += bf2f(h[(size_t)r * 64 + c]);
  __shared__ float red[4][64];
  __shared__ float pooled[64];
  red[wv][c] = acc;
  __syncthreads();
  if (t < 64) {
    float cntf = (float)max(e - s, 1);
    pooled[t] = (red[0][t] + red[1][t] + red[2][t] + red[3][t]) / cntf;
  }
  __syncthreads();
  if (t < 32) {
    float a = bo[t];
#pragma unroll 8
    for (int k = 0; k < 64; ++k) a += pooled[k] * Wo[k * 32 + t];
    out[g * 32 + t] = a;
  }
}

extern "C" void kernel_launch(void* const* d_in, const int* in_sizes, int n_in,
                              void* d_out, int out_size, void* d_ws, size_t ws_size,
                              hipStream_t stream) {
  const float* x     = (const float*)d_in[0];
  const int*   ei    = (const int*)d_in[1];
  const int*   batch = (const int*)d_in[2];
  const float* Wp    = (const float*)d_in[3];
  const float* bp    = (const float*)d_in[4];
  const float* Wo    = (const float*)d_in[5];
  const float* bo    = (const float*)d_in[6];
  const float* Wl[3]  = {(const float*)d_in[7],  (const float*)d_in[11], (const float*)d_in[15]};
  const float* Asl[3] = {(const float*)d_in[8],  (const float*)d_in[12], (const float*)d_in[16]};
  const float* Adl[3] = {(const float*)d_in[9],  (const float*)d_in[13], (const float*)d_in[17]};
  const float* Bl[3]  = {(const float*)d_in[10], (const float*)d_in[14], (const float*)d_in[18]};

  const int N = in_sizes[0] / 16;   // 50000
  const int E = in_sizes[1] / 2;    // 800000
  const int G = out_size / 32;      // 64
  const int Et = E + N;             // edges incl. self loops
  const int* src = ei;
  const int* dst = ei + E;
  const int NB = (N + 1023) / 1024; // scan blocks (<=64)

  // workspace carve (256B aligned)
  char* ws = (char*)d_ws;
  size_t off = 0;
  auto take = [&](size_t bytes) -> void* {
    void* p = ws + off;
    off = (off + bytes + 255) & ~(size_t)255;
    return p;
  };
  unsigned short* h_a = (unsigned short*)take((size_t)N * 64 * 2);
  unsigned short* h_b = (unsigned short*)take((size_t)N * 64 * 2);
  unsigned short* hwb = (unsigned short*)take((size_t)N * 256 * 2);
  float* alS   = (float*)take((size_t)N * 4 * 4);
  float* alD   = (float*)take((size_t)N * 4 * 4);
  int*   deg   = (int*)take((size_t)N * 4);
  int*   cnt   = (int*)take((size_t)N * 4);
  int*   rowp  = (int*)take((size_t)(N + 1) * 4);
  int*   col   = (int*)take((size_t)Et * 4);
  int*   bsum  = (int*)take((size_t)64 * 4);
  int*   bpre  = (int*)take((size_t)65 * 4);
  unsigned short* Wsw  = (unsigned short*)take((size_t)3 * 16384 * 2);
  unsigned short* Wasw = (unsigned short*)take((size_t)3 * 1024 * 2);
  (void)ws_size; (void)n_in;

  // weight prep (blocks 0-2) + deg zero-fill (blocks 3+), one launch
  prep_kernel<<<3 + (N + 1023) / 1024, 256, 0, stream>>>(
      Wl[0], Asl[0], Adl[0], Wl[1], Asl[1], Adl[1], Wl[2], Asl[2], Adl[2],
      Wsw, Wasw, deg, N);

  // CSR build (scalar atomics: 1 edge/thread)
  hist_kernel<<<(E + 255) / 256, 256, 0, stream>>>(dst, deg, E);
  scan_a<<<NB, 256, 0, stream>>>(deg, rowp, bsum, N);
  scan_b<<<1, 64, 0, stream>>>(bsum, bpre, NB);
  scan_c<<<(N + 255) / 256, 256, 0, stream>>>(rowp, bpre, cnt, col, N);
  scatter_kernel<<<(E + 255) / 256, 256, 0, stream>>>(src, dst, rowp, cnt, col, E);

  // 3 GAT layers (layer 0 fuses the input projection; no h0 buffer round-trip)
  hw_kernel<true><<<(N + 63) / 64, 256, 0, stream>>>(nullptr, x, Wp, bp,
                                                     Wsw, Wasw, hwb, alS, alD, N);
  gat_agg<<<(N + 3) / 4, 256, 0, stream>>>(rowp, col, alS, alD, hwb, Bl[0], h_b, N);
  hw_kernel<false><<<(N + 63) / 64, 256, 0, stream>>>(h_b, nullptr, nullptr, nullptr,
                                                      Wsw + 16384, Wasw + 1024, hwb, alS, alD, N);
  gat_agg<<<(N + 3) / 4, 256, 0, stream>>>(rowp, col, alS, alD, hwb, Bl[1], h_a, N);
  hw_kernel<false><<<(N + 63) / 64, 256, 0, stream>>>(h_a, nullptr, nullptr, nullptr,
                                                      Wsw + 32768, Wasw + 2048, hwb, alS, alD, N);
  gat_agg<<<(N + 3) / 4, 256, 0, stream>>>(rowp, col, alS, alD, hwb, Bl[2], h_b, N);

  // fused pooling + output projection (no memsets, no atomics)
  poolout_kernel<<<G, 256, 0, stream>>>(h_b, batch, Wo, bo, (float*)d_out, N);
}

// Round 13
// 414.652 us; speedup vs baseline: 1.0558x; 1.0558x over previous
//
#include <hip/hip_runtime.h>

#define NEG_SLOPE 0.2f

typedef __attribute__((ext_vector_type(8))) short bf16x8;
typedef __attribute__((ext_vector_type(8))) unsigned short u16x8;
typedef __attribute__((ext_vector_type(4))) float f32x4;

__device__ __forceinline__ float lrelu(float x) { return fmaxf(x, NEG_SLOPE * x); }

__device__ __forceinline__ float bf2f(unsigned short u) {
  return __uint_as_float(((unsigned int)u) << 16);
}
__device__ __forceinline__ unsigned short f2bf(float f) {
  unsigned int u = __float_as_uint(f);
  u += 0x7fffu + ((u >> 16) & 1u);   // round-to-nearest-even
  return (unsigned short)(u >> 16);
}

// ---------------- h0 = relu(x @ Wp + bp) : [N,16]@[16,64], bf16 out ----------------
__global__ void proj_kernel(const float* __restrict__ x, const float* __restrict__ Wp,
                            const float* __restrict__ bp, unsigned short* __restrict__ h,
                            int n_nodes) {
  int idx = blockIdx.x * blockDim.x + threadIdx.x;
  int n = idx >> 6, c = idx & 63;
  if (n >= n_nodes) return;
  float acc = bp[c];
#pragma unroll
  for (int k = 0; k < 16; ++k) acc += x[n * 16 + k] * Wp[k * 64 + c];
  h[n * 64 + c] = f2bf(fmaxf(acc, 0.f));
}

// ---------------- CSR build (by destination), self-loop first ----------------
__global__ void hist_kernel(const int* __restrict__ dst, int* __restrict__ deg, int e) {
  int i = blockIdx.x * blockDim.x + threadIdx.x;
  if (i < e) atomicAdd(&deg[dst[i]], 1);
}

// phase A: per-block (1024 elems) local exclusive scan of (deg[i]+1); block sums out.
__global__ __launch_bounds__(256) void scan_a(const int* __restrict__ deg, int* __restrict__ rowp,
                                              int* __restrict__ bsum, int n) {
  __shared__ int s[256];
  int t = threadIdx.x;
  int base = blockIdx.x * 1024 + t * 4;
  int d0 = (base + 0 < n) ? deg[base + 0] + 1 : 0;
  int d1 = (base + 1 < n) ? deg[base + 1] + 1 : 0;
  int d2 = (base + 2 < n) ? deg[base + 2] + 1 : 0;
  int d3 = (base + 3 < n) ? deg[base + 3] + 1 : 0;
  s[t] = d0 + d1 + d2 + d3;
  __syncthreads();
  for (int off = 1; off < 256; off <<= 1) {
    int v = 0;
    if (t >= off) v = s[t - off];
    __syncthreads();
    if (t >= off) s[t] += v;
    __syncthreads();
  }
  int p = (t == 0) ? 0 : s[t - 1];
  if (base + 0 < n) rowp[base + 0] = p;
  p += d0;
  if (base + 1 < n) rowp[base + 1] = p;
  p += d1;
  if (base + 2 < n) rowp[base + 2] = p;
  p += d2;
  if (base + 3 < n) rowp[base + 3] = p;
  if (t == 255) bsum[blockIdx.x] = s[255];
}

// phase B: single wave exclusive-scans <=64 block sums; bpre[64] = grand total.
__global__ void scan_b(const int* __restrict__ bsum, int* __restrict__ bpre, int nb) {
  int t = threadIdx.x;  // 64 threads = 1 wave
  int v = (t < nb) ? bsum[t] : 0;
  int orig = v;
#pragma unroll
  for (int off = 1; off < 64; off <<= 1) {
    int u = __shfl_up(v, off);
    if (t >= off) v += u;
  }
  bpre[t] = v - orig;
  if (t == 63) bpre[64] = v;
}

// phase C: add block prefixes; fused init_csr (self-loop slot 0).
__global__ void scan_c(int* __restrict__ rowp, const int* __restrict__ bpre,
                       int* __restrict__ cnt, int* __restrict__ col, int n) {
  int i = blockIdx.x * blockDim.x + threadIdx.x;
  if (i < n) {
    int r = rowp[i] + bpre[i >> 10];
    rowp[i] = r;
    cnt[i] = 1;       // slot 0 = self loop
    col[r] = i;
  }
  if (i == 0) rowp[n] = bpre[64];
}

__global__ void scatter_kernel(const int* __restrict__ src, const int* __restrict__ dst,
                               const int* __restrict__ rowp, int* __restrict__ cnt,
                               int* __restrict__ col, int e) {
  int i = blockIdx.x * blockDim.x + threadIdx.x;
  if (i < e) {
    int d = dst[i];
    int pos = rowp[d] + atomicAdd(&cnt[d], 1);
    col[pos] = src[i];
  }
}

// ---------------- fused: fold a_src/a_dst into W, then swizzle W & Wa to MFMA B-frag (bf16) ----
__global__ __launch_bounds__(256) void prep_kernel(
    const float* __restrict__ W0, const float* __restrict__ as0, const float* __restrict__ ad0,
    const float* __restrict__ W1, const float* __restrict__ as1, const float* __restrict__ ad1,
    const float* __restrict__ W2, const float* __restrict__ as2, const float* __restrict__ ad2,
    unsigned short* __restrict__ Wsw, unsigned short* __restrict__ Wasw) {
  __shared__ float wa[512];
  int l = blockIdx.x;
  const float* W  = l == 0 ? W0  : l == 1 ? W1  : W2;
  const float* as = l == 0 ? as0 : l == 1 ? as1 : as2;
  const float* ad = l == 0 ? ad0 : l == 1 ? ad1 : ad2;
  int t = threadIdx.x;          // 256 threads
  {
    int k = t >> 2, h = t & 3;
    float ss = 0.f, sd = 0.f;
    for (int c = 0; c < 64; ++c) {
      float w = W[k * 256 + h * 64 + c];
      ss += w * as[h * 64 + c];
      sd += w * ad[h * 64 + c];
    }
    wa[k * 8 + h] = ss;
    wa[k * 8 + 4 + h] = sd;
  }
  __syncthreads();
  for (int s = t; s < 2048; s += 256) {
    int nt = s >> 7, kk = (s >> 6) & 1, lane = s & 63;
    int kq = lane >> 4, r = lane & 15;
#pragma unroll
    for (int j = 0; j < 8; ++j) {
      int k = kk * 32 + kq * 8 + j;
      Wsw[(size_t)l * 16384 + (size_t)s * 8 + j] = f2bf(W[k * 256 + nt * 16 + r]);
    }
  }
  if (t < 128) {
    int lane = t & 63, kq = lane >> 4, r = lane & 15;
    int kk = t >> 6;
#pragma unroll
    for (int j = 0; j < 8; ++j) {
      int k = kk * 32 + kq * 8 + j;
      float v = (r < 8) ? wa[k * 8 + r] : 0.f;
      Wasw[l * 1024 + t * 8 + j] = f2bf(v);
    }
  }
}

// ---------------- hw(bf16) = h @ W via MFMA + attention logits ----------------
// Epilogue: stage bf16 results in LDS (padded rows), then coalesced 16B row-streaming stores.
__global__ __launch_bounds__(256) void hw_kernel(const unsigned short* __restrict__ hb,
                                                 const unsigned short* __restrict__ Wsw,
                                                 const unsigned short* __restrict__ Wasw,
                                                 unsigned short* __restrict__ hwb,
                                                 float* __restrict__ al_s, float* __restrict__ al_d,
                                                 int n_nodes) {
  __shared__ unsigned short st[64][264];   // 256 cols + 8 pad (keeps 16B align, spreads banks)
  int t = threadIdx.x;
  int w = t >> 6, lane = t & 63;
  int kq = lane >> 4, r16 = lane & 15;
  int n0 = blockIdx.x << 6;

  // A fragments: 4 m-tiles x 2 k-steps; direct 16B loads from row-major bf16 h
  bf16x8 a[4][2];
#pragma unroll
  for (int m = 0; m < 4; ++m) {
    int row = min(n0 + m * 16 + r16, n_nodes - 1);
    const unsigned short* p = hb + (size_t)row * 64 + kq * 8;
    a[m][0] = *(const bf16x8*)(p);
    a[m][1] = *(const bf16x8*)(p + 32);
  }
  // B fragments: 4 local n-tiles x 2 k-steps
  bf16x8 b[4][2];
#pragma unroll
  for (int nt = 0; nt < 4; ++nt) {
    int ntg = w * 4 + nt;
    const unsigned short* p = Wsw + ((size_t)ntg * 128 + lane) * 8;
    b[nt][0] = *(const bf16x8*)(p);
    b[nt][1] = *(const bf16x8*)(p + 512);
  }

  f32x4 acc[4][4];
#pragma unroll
  for (int m = 0; m < 4; ++m)
#pragma unroll
    for (int nt = 0; nt < 4; ++nt) acc[m][nt] = (f32x4){0.f, 0.f, 0.f, 0.f};

#pragma unroll
  for (int m = 0; m < 4; ++m)
#pragma unroll
    for (int nt = 0; nt < 4; ++nt) {
      acc[m][nt] = __builtin_amdgcn_mfma_f32_16x16x32_bf16(a[m][0], b[nt][0], acc[m][nt], 0, 0, 0);
      acc[m][nt] = __builtin_amdgcn_mfma_f32_16x16x32_bf16(a[m][1], b[nt][1], acc[m][nt], 0, 0, 0);
    }

  // stage C into LDS (C/D mapping: col=lane&15, row=(lane>>4)*4+reg)
#pragma unroll
  for (int m = 0; m < 4; ++m)
#pragma unroll
    for (int j = 0; j < 4; ++j) {
      int row = m * 16 + kq * 4 + j;
#pragma unroll
      for (int nt = 0; nt < 4; ++nt)
        st[row][(w * 4 + nt) * 16 + r16] = f2bf(acc[m][nt][j]);
    }
  __syncthreads();

  // coalesced stores: each instr = 32 lanes x 16B = one full 512B row; wave does 2 rows/iter
  int rmax = min(64, n_nodes - n0);
  for (int i = t; i < (rmax << 5); i += 256) {
    int row = i >> 5, ch = i & 31;
    *(u16x8*)(hwb + (size_t)(n0 + row) * 256 + ch * 8) = *(const u16x8*)(&st[row][ch * 8]);
  }

  // attention logits: wave w handles m-tile w; B = folded Wa (8 valid cols)
  bf16x8 ba0 = *(const bf16x8*)(Wasw + lane * 8);
  bf16x8 ba1 = *(const bf16x8*)(Wasw + (64 + lane) * 8);
  f32x4 accl = (f32x4){0.f, 0.f, 0.f, 0.f};
  accl = __builtin_amdgcn_mfma_f32_16x16x32_bf16(a[w][0], ba0, accl, 0, 0, 0);
  accl = __builtin_amdgcn_mfma_f32_16x16x32_bf16(a[w][1], ba1, accl, 0, 0, 0);
  if (r16 < 8) {
#pragma unroll
    for (int j = 0; j < 4; ++j) {
      int row = n0 + w * 16 + kq * 4 + j;
      if (row < n_nodes) {
        if (r16 < 4) al_s[row * 4 + r16] = accl[j];
        else         al_d[row * 4 + (r16 - 4)] = accl[j];
      }
    }
  }
}

// ---------------- aggregate: wave per node, two edges per iteration ----------------
__global__ __launch_bounds__(256) void gat_agg(const int* __restrict__ rowp, const int* __restrict__ col,
                                               const float* __restrict__ alS, const float* __restrict__ alD,
                                               const unsigned short* __restrict__ hwb,
                                               const float* __restrict__ bias,
                                               unsigned short* __restrict__ hout,
                                               int n_nodes) {
  __shared__ uint2 pw[4][64 * 4];   // [wave][edge*4 + head] = (byte addr, w)
  int t = threadIdx.x;
  int wslot = t >> 6, lane = t & 63;
  int node = blockIdx.x * 4 + wslot;
  if (node >= n_nodes) return;      // whole wave exits together
  int base = rowp[node];
  int degv = rowp[node + 1] - base;
  int l31 = lane & 31;
  int half = lane >> 5;                               // which edge of the pair
  int headw = l31 >> 3;                               // head owning this lane's 8 channels
  unsigned int laneoff = (unsigned int)l31 << 4;      // 16B per lane within 512B row
  float4 ald4 = *(const float4*)(alD + (size_t)node * 4);

  float a0 = 0.f, a1 = 0.f, a2 = 0.f, a3 = 0.f;
  float a4 = 0.f, a5 = 0.f, a6 = 0.f, a7 = 0.f, denom = 0.f;

  for (int c0 = 0; c0 < degv; c0 += 64) {
    int cnt = min(64, degv - c0);
    {
      unsigned int ab = 0u;
      float w0 = 0.f, w1 = 0.f, w2 = 0.f, w3 = 0.f;
      if (lane < cnt) {
        int s = col[base + c0 + lane];                // coalesced
        float4 as4 = *(const float4*)(alS + (size_t)s * 4);
        ab = (unsigned int)s << 9;                    // byte addr of hwb row
        w0 = __expf(lrelu(as4.x + ald4.x));
        w1 = __expf(lrelu(as4.y + ald4.y));
        w2 = __expf(lrelu(as4.z + ald4.z));
        w3 = __expf(lrelu(as4.w + ald4.w));
      }
      uint4* pd = (uint4*)&pw[wslot][lane * 4];
      pd[0] = make_uint4(ab, __float_as_uint(w0), ab, __float_as_uint(w1));
      pd[1] = make_uint4(ab, __float_as_uint(w2), ab, __float_as_uint(w3));
    }
    // wave-synchronous: same wave wrote, same wave reads (lgkmcnt auto-inserted)
    int iters = (cnt + 1) >> 1;
#pragma unroll 4
    for (int i = 0; i < iters; ++i) {
      int e = i * 2 + half;
      uint2 p = pw[wslot][e * 4 + headw];             // one ds_read_b64
      float w = __uint_as_float(p.y);
      uint4 v = *(const uint4*)((const char*)hwb + (p.x + laneoff));  // independent gather
      denom += w;
      a0 += w * __uint_as_float(v.x << 16);
      a1 += w * __uint_as_float(v.x & 0xffff0000u);
      a2 += w * __uint_as_float(v.y << 16);
      a3 += w * __uint_as_float(v.y & 0xffff0000u);
      a4 += w * __uint_as_float(v.z << 16);
      a5 += w * __uint_as_float(v.z & 0xffff0000u);
      a6 += w * __uint_as_float(v.w << 16);
      a7 += w * __uint_as_float(v.w & 0xffff0000u);
    }
  }

  // fold the two halves (edge-interleave), then per-head normalize
  denom += __shfl_xor(denom, 32);
  a0 += __shfl_xor(a0, 32); a1 += __shfl_xor(a1, 32);
  a2 += __shfl_xor(a2, 32); a3 += __shfl_xor(a3, 32);
  a4 += __shfl_xor(a4, 32); a5 += __shfl_xor(a5, 32);
  a6 += __shfl_xor(a6, 32); a7 += __shfl_xor(a7, 32);
  float inv = 1.f / denom;
  a0 *= inv; a1 *= inv; a2 *= inv; a3 *= inv;
  a4 *= inv; a5 *= inv; a6 *= inv; a7 *= inv;

  // head mean: channel (l31&7)*8+j lives at lanes {l31&7, +8, +16, +24}
  a0 += __shfl_xor(a0, 8); a0 += __shfl_xor(a0, 16);
  a1 += __shfl_xor(a1, 8); a1 += __shfl_xor(a1, 16);
  a2 += __shfl_xor(a2, 8); a2 += __shfl_xor(a2, 16);
  a3 += __shfl_xor(a3, 8); a3 += __shfl_xor(a3, 16);
  a4 += __shfl_xor(a4, 8); a4 += __shfl_xor(a4, 16);
  a5 += __shfl_xor(a5, 8); a5 += __shfl_xor(a5, 16);
  a6 += __shfl_xor(a6, 8); a6 += __shfl_xor(a6, 16);
  a7 += __shfl_xor(a7, 8); a7 += __shfl_xor(a7, 16);

  if (lane < 8) {
    const float* bp = bias + lane * 8;
    float4 b0 = *(const float4*)(bp);
    float4 b1 = *(const float4*)(bp + 4);
    ushort4 o0, o1;
    o0.x = f2bf(fmaxf(0.25f * a0 + b0.x, 0.f));
    o0.y = f2bf(fmaxf(0.25f * a1 + b0.y, 0.f));
    o0.z = f2bf(fmaxf(0.25f * a2 + b0.z, 0.f));
    o0.w = f2bf(fmaxf(0.25f * a3 + b0.w, 0.f));
    o1.x = f2bf(fmaxf(0.25f * a4 + b1.x, 0.f));
    o1.y = f2bf(fmaxf(0.25f * a5 + b1.y, 0.f));
    o1.z = f2bf(fmaxf(0.25f * a6 + b1.z, 0.f));
    o1.w = f2bf(fmaxf(0.25f * a7 + b1.w, 0.f));
    unsigned short* op = hout + (size_t)node * 64 + lane * 8;
    *(ushort4*)(op) = o0;
    *(ushort4*)(op + 4) = o1;
  }
}

// ---------------- global mean pool (batch is sorted), bf16 in ----------------
__global__ void pool_kernel(const unsigned short* __restrict__ h, const int* __restrict__ batch,
                            float* __restrict__ pool, float* __restrict__ pcnt, int n_nodes) {
  int c = threadIdx.x;  // 64 threads
  int n0 = blockIdx.x * 64;
  int n1 = min(n0 + 64, n_nodes);
  float acc = 0.f;
  int run = 0;
  int gcur = batch[n0];
  for (int n = n0; n < n1; ++n) {
    int g = batch[n];
    if (g != gcur) {
      atomicAdd(&pool[gcur * 64 + c], acc);
      if (c == 0) atomicAdd(&pcnt[gcur], (float)run);
      acc = 0.f; run = 0; gcur = g;
    }
    acc += bf2f(h[(size_t)n * 64 + c]);
    ++run;
  }
  atomicAdd(&pool[gcur * 64 + c], acc);
  if (c == 0) atomicAdd(&pcnt[gcur], (float)run);
}

// ---------------- out = (pool/cnt) @ Wo + bo : [G,64]@[64,32] ----------------
__global__ void out_kernel(const float* __restrict__ pool, const float* __restrict__ pcnt,
                           const float* __restrict__ Wo, const float* __restrict__ bo,
                           float* __restrict__ out, int g_total) {
  int idx = blockIdx.x * blockDim.x + threadIdx.x;
  if (idx >= g_total * 32) return;
  int g = idx >> 5, d = idx & 31;
  float inv = 1.f / fmaxf(pcnt[g], 1.f);
  float acc = bo[d];
#pragma unroll
  for (int c = 0; c < 64; ++c) acc += (pool[g * 64 + c] * inv) * Wo[c * 32 + d];
  out[idx] = acc;
}

extern "C" void kernel_launch(void* const* d_in, const int* in_sizes, int n_in,
                              void* d_out, int out_size, void* d_ws, size_t ws_size,
                              hipStream_t stream) {
  const float* x     = (const float*)d_in[0];
  const int*   ei    = (const int*)d_in[1];
  const int*   batch = (const int*)d_in[2];
  const float* Wp    = (const float*)d_in[3];
  const float* bp    = (const float*)d_in[4];
  const float* Wo    = (const float*)d_in[5];
  const float* bo    = (const float*)d_in[6];
  const float* Wl[3]  = {(const float*)d_in[7],  (const float*)d_in[11], (const float*)d_in[15]};
  const float* Asl[3] = {(const float*)d_in[8],  (const float*)d_in[12], (const float*)d_in[16]};
  const float* Adl[3] = {(const float*)d_in[9],  (const float*)d_in[13], (const float*)d_in[17]};
  const float* Bl[3]  = {(const float*)d_in[10], (const float*)d_in[14], (const float*)d_in[18]};

  const int N = in_sizes[0] / 16;   // 50000
  const int E = in_sizes[1] / 2;    // 800000
  const int G = out_size / 32;      // 64
  const int Et = E + N;             // edges incl. self loops
  const int* src = ei;
  const int* dst = ei + E;
  const int NB = (N + 1023) / 1024; // scan blocks (<=64)

  // workspace carve (256B aligned)
  char* ws = (char*)d_ws;
  size_t off = 0;
  auto take = [&](size_t bytes) -> void* {
    void* p = ws + off;
    off = (off + bytes + 255) & ~(size_t)255;
    return p;
  };
  unsigned short* h_a = (unsigned short*)take((size_t)N * 64 * 2);
  unsigned short* h_b = (unsigned short*)take((size_t)N * 64 * 2);
  unsigned short* hwb = (unsigned short*)take((size_t)N * 256 * 2);
  float* alS   = (float*)take((size_t)N * 4 * 4);
  float* alD   = (float*)take((size_t)N * 4 * 4);
  int*   deg   = (int*)take((size_t)N * 4);
  int*   cnt   = (int*)take((size_t)N * 4);
  int*   rowp  = (int*)take((size_t)(N + 1) * 4);
  int*   col   = (int*)take((size_t)Et * 4);
  int*   bsum  = (int*)take((size_t)64 * 4);
  int*   bpre  = (int*)take((size_t)65 * 4);
  unsigned short* Wsw  = (unsigned short*)take((size_t)3 * 16384 * 2);
  unsigned short* Wasw = (unsigned short*)take((size_t)3 * 1024 * 2);
  float* pool  = (float*)take((size_t)G * 64 * 4);
  float* pcnt  = (float*)take((size_t)G * 4);
  (void)ws_size; (void)n_in;

  // fold attention vectors + swizzle weights (one fused launch)
  prep_kernel<<<3, 256, 0, stream>>>(Wl[0], Asl[0], Adl[0], Wl[1], Asl[1], Adl[1],
                                     Wl[2], Asl[2], Adl[2], Wsw, Wasw);

  // CSR build (self-loop +1 folded into scan_a; init_csr folded into scan_c)
  hipMemsetAsync(deg, 0, (size_t)N * 4, stream);
  hist_kernel<<<(E + 255) / 256, 256, 0, stream>>>(dst, deg, E);
  scan_a<<<NB, 256, 0, stream>>>(deg, rowp, bsum, N);
  scan_b<<<1, 64, 0, stream>>>(bsum, bpre, NB);
  scan_c<<<(N + 255) / 256, 256, 0, stream>>>(rowp, bpre, cnt, col, N);
  scatter_kernel<<<(E + 255) / 256, 256, 0, stream>>>(src, dst, rowp, cnt, col, E);

  // input projection
  proj_kernel<<<((size_t)N * 64 + 255) / 256, 256, 0, stream>>>(x, Wp, bp, h_a, N);

  // 3 GAT layers
  const unsigned short* hin = h_a;
  unsigned short* hout = h_b;
  for (int l = 0; l < 3; ++l) {
    hw_kernel<<<(N + 63) / 64, 256, 0, stream>>>(hin, Wsw + (size_t)l * 16384,
                                                 Wasw + (size_t)l * 1024, hwb, alS, alD, N);
    gat_agg<<<(N + 3) / 4, 256, 0, stream>>>(rowp, col, alS, alD, hwb, Bl[l], hout, N);
    const unsigned short* tmp = hout;
    hout = (unsigned short*)hin;
    hin = tmp;
  }

  // pooling + output projection (single memset covers pool..pcnt span)
  hipMemsetAsync(pool, 0, (size_t)((char*)(pcnt + G) - (char*)pool), stream);
  pool_kernel<<<(N + 63) / 64, 64, 0, stream>>>(hin, batch, pool, pcnt, N);
  out_kernel<<<(G * 32 + 255) / 256, 256, 0, stream>>>(pool, pcnt, Wo, bo, (float*)d_out, G);
}